// Round 5
// baseline (1135.848 us; speedup 1.0000x reference)
//
#include <hip/hip_runtime.h>
#include <hip/hip_bf16.h>
#include <math.h>

// Problem: S=512, B=128, V=50257, D=300, H=512
#define S_LEN 512
#define B_N   128
#define D_EMB 300
#define KP    320   // D padded to multiple of 32 (zero-filled)
#define H_N   512

typedef __attribute__((ext_vector_type(8)))  short short8;       // 8 bf16 (4 VGPRs)
typedef __attribute__((ext_vector_type(8)))  unsigned short ushort8;
typedef __attribute__((ext_vector_type(4)))  unsigned int uint4v;
typedef __attribute__((ext_vector_type(4)))  float float4v;
typedef __attribute__((ext_vector_type(16))) float float16v;

__device__ __forceinline__ unsigned short f32_to_bf16(float f) {
  unsigned u = __float_as_uint(f);
  u = (u + 0x7fffu + ((u >> 16) & 1u)) >> 16;   // RNE
  return (unsigned short)u;
}
__device__ __forceinline__ float bf16_to_f32(unsigned short h) {
  return __uint_as_float(((unsigned)h) << 16);
}
__device__ __forceinline__ short8 as_short8(uint4v v) {
  union { uint4v u; short8 s; } c; c.u = v; return c.s;
}

// ---------------------------------------------------------------------------
// K1: embeds = embed_mat[ends]; xn = embeds / max(||embeds||,eps)
// writes xn as split bf16 (hi+lo), layout [b][s][KP], k 300..319 zero.
// ---------------------------------------------------------------------------
__global__ __launch_bounds__(256) void k1_embed_norm(
    const int* __restrict__ ends, const float* __restrict__ emb,
    unsigned short* __restrict__ xh, unsigned short* __restrict__ xl) {
  int wave = threadIdx.x >> 6, lane = threadIdx.x & 63;
  int vec = blockIdx.x * 4 + wave;            // vec = s*B + b (ends is [S][B])
  int b = vec & (B_N - 1), s = vec >> 7;
  int v = ends[vec];
  const float* row = emb + (size_t)v * D_EMB;
  float e0 = row[lane], e1 = row[lane + 64], e2 = row[lane + 128], e3 = row[lane + 192];
  float e4 = (lane + 256 < D_EMB) ? row[lane + 256] : 0.f;
  float ss = e0*e0 + e1*e1 + e2*e2 + e3*e3 + e4*e4;
  #pragma unroll
  for (int m = 1; m < 64; m <<= 1) ss += __shfl_xor(ss, m);
  float sc = 1.0f / fmaxf(sqrtf(ss), 1e-8f);
  size_t base = ((size_t)b * S_LEN + s) * KP;
  float xs[5] = { e0*sc, e1*sc, e2*sc, e3*sc, (lane + 256 < D_EMB) ? e4*sc : 0.f };
  #pragma unroll
  for (int i = 0; i < 5; ++i) {
    unsigned short hi = f32_to_bf16(xs[i]);
    unsigned short lo = f32_to_bf16(xs[i] - bf16_to_f32(hi));
    xh[base + lane + 64*i] = hi;
    xl[base + lane + 64*i] = lo;
  }
}

// ---------------------------------------------------------------------------
// K2: feats[i][b] = max_{j<i} dot(xn[i,b], xn[j,b]); feats[0]=0
// Split-bf16 MFMA 32x32x16 (hi*hi + hi*lo + lo*hi).
// R11: A-operand fragments loaded straight from global into registers
// (identical element mapping as the old LDS path; L2-hot after jc=0),
// LDS stages only B (22.5KB -> ~2x co-residency), grid is (b, ic) so all
// ic-chunks of a batch share one XCD L2 (same %8 mapping k3 relies on).
// ---------------------------------------------------------------------------
#define KC  80
#define LDP 88      // LDS row stride in ushorts (conflict-friendly, 16B aligned)

__global__ __launch_bounds__(256) void k2_feats(
    const unsigned short* __restrict__ xh, const unsigned short* __restrict__ xl,
    float* __restrict__ feats) {
  __shared__ __align__(16) unsigned short sBh[64*LDP], sBl[64*LDP];
  __shared__ float rbuf[4][32];
  int b   = blockIdx.x;          // 0..127 (b&7 selects XCD)
  int ic  = blockIdx.y;          // 0..7
  int tid = threadIdx.x;
  int wave = tid >> 6, lane = tid & 63;
  int itl = wave & 1, jtl = wave >> 1;
  int itg = ic * 2 + itl;        // global 32-row i-tile index
  size_t xbase = (size_t)b * S_LEN * KP;
  int arow0 = ic * 64;
  // my A row (m = lane&31) and k-quad offset
  const size_t arowoff = xbase + (size_t)(arow0 + itl * 32 + (lane & 31)) * KP
                       + (size_t)((lane >> 5) * 8);

  float rm[16];
  #pragma unroll
  for (int r = 0; r < 16; ++r) rm[r] = -INFINITY;

  for (int jc = 0; jc <= ic; ++jc) {
    int jt = jc * 2 + jtl;
    bool active = (jt <= itg);
    float16v acc;
    #pragma unroll
    for (int r = 0; r < 16; ++r) acc[r] = 0.f;

    for (int kc = 0; kc < 4; ++kc) {
      // A fragments: direct global->register (10 x 16B per lane)
      short8 a_h[5], a_l[5];
      #pragma unroll
      for (int ks = 0; ks < 5; ++ks) {
        size_t ga = arowoff + kc * KC + ks * 16;
        a_h[ks] = *(const short8*)&xh[ga];
        a_l[ks] = *(const short8*)&xl[ga];
      }
      __syncthreads();
      for (int u = tid; u < 640; u += 256) {     // 64 rows x 10 16B-segs (B only)
        int r = u / 10, sg = u % 10;
        size_t gb = xbase + (size_t)(jc*64 + r) * KP + kc*KC + sg*8;
        int la = r * LDP + sg * 8;
        *(ushort8*)&sBh[la] = *(const ushort8*)&xh[gb];
        *(ushort8*)&sBl[la] = *(const ushort8*)&xl[gb];
      }
      __syncthreads();
      if (active) {
        int br = (jtl*32 + (lane & 31)) * LDP;
        int kq = (lane >> 5) * 8;
        #pragma unroll
        for (int ks = 0; ks < 5; ++ks) {
          short8 b_h = *(const short8*)&sBh[br + ks*16 + kq];
          short8 b_l = *(const short8*)&sBl[br + ks*16 + kq];
          acc = __builtin_amdgcn_mfma_f32_32x32x16_bf16(a_h[ks], b_h, acc, 0, 0, 0);
          acc = __builtin_amdgcn_mfma_f32_32x32x16_bf16(a_h[ks], b_l, acc, 0, 0, 0);
          acc = __builtin_amdgcn_mfma_f32_32x32x16_bf16(a_l[ks], b_h, acc, 0, 0, 0);
        }
      }
    }
    if (active) {
      int colg = jt * 32 + (lane & 31);
      #pragma unroll
      for (int r = 0; r < 16; ++r) {
        int rowg = itg * 32 + (r & 3) + 8*(r >> 2) + 4*(lane >> 5);
        float v = acc[r];
        if (jt == itg && colg >= rowg) v = -INFINITY;  // causal: j<i
        rm[r] = fmaxf(rm[r], v);
      }
    }
  }
  #pragma unroll
  for (int r = 0; r < 16; ++r) {
    float v = rm[r];
    v = fmaxf(v, __shfl_xor(v, 1));
    v = fmaxf(v, __shfl_xor(v, 2));
    v = fmaxf(v, __shfl_xor(v, 4));
    v = fmaxf(v, __shfl_xor(v, 8));
    v = fmaxf(v, __shfl_xor(v, 16));
    rm[r] = v;
  }
  if ((lane & 31) == 0) {
    int half = lane >> 5;
    #pragma unroll
    for (int r = 0; r < 16; ++r)
      rbuf[wave][(r & 3) + 8*(r >> 2) + 4*half] = rm[r];
  }
  __syncthreads();
  if (tid < 64) {   // merge jt-parities, write feats
    int it2 = tid >> 5, rl = tid & 31;
    float v = fmaxf(rbuf[it2][rl], rbuf[it2 + 2][rl]);
    int i = ic * 64 + it2 * 32 + rl;
    feats[i * B_N + b] = (i == 0) ? 0.0f : v;
  }
}

// ---------------------------------------------------------------------------
// K3: GRU, persistent cooperative kernel. 256 WGs x 256 thr.
// FROZEN R8 signal skeleton: wg-scope producer stores -> vmcnt(0) ->
// __syncthreads -> tid0 WG-flag store; consumer flag poll with s_sleep.
// LEDGER: per-wave PRODUCER flag fanouts fast-fail 3/3 (R5/R6/R9);
// counter-RMW flags regress (R10); poison-spin data-as-signal +16% (R12);
// R13 coalesced consumer load -360us; R14 fragment-major layout -253us;
// R15 bank-conflict-free reduce (2.5e7 -> 0) only -19us => conflicts were
// overlapped, NOT critical path; per-wave poll can't absorb skew (red2
// barrier recouples waves; h needs all K=512 -> period = max over all 32).
// R16 (this round): MFMA-chain + load-pipeline fix, skeleton untouched.
//   Counters showed 16.3 cy/MFMA (MfmaUtil 14.9% x 3933cy / 36) vs ~5 issue:
//   12-deep dep chains, 3-way interleave -> ~11cy stall per MFMA.
//   a) 6 accumulator chains (ks01 -> b, ks23 -> c, merge a=b+c): same-acc
//      spacing 6 issues >= latency -> stalls gone (~400cy/step).
//   b) staged loads: order h0,l0,h2,l2,h1,l1,h3,l3; vmcnt(4)+sched_barrier
//      -> 18 MFMAs (ks0,ks2) overlap the ks1,ks3 loads; vmcnt(0) -> rest.
//      (rule #18: sched_barrier(0) after each manual waitcnt.)
// ---------------------------------------------------------------------------
#define HW64 (B_N * H_N / 2)   // 8B words per parity buffer (= 32768)

__global__ __launch_bounds__(256, 1) void k3_gru(
    const float* __restrict__ feats,
    const float* __restrict__ w_ih, const float* __restrict__ w_hh,
    const float* __restrict__ b_ih, const float* __restrict__ b_hh,
    const float* __restrict__ fc_w, const float* __restrict__ fc_b,
    unsigned long long* __restrict__ hq, unsigned int* __restrict__ bars,
    float* __restrict__ out) {
  __shared__ __align__(16) float4v red2[4][16][16];   // [wave][batch][j] = {r,z,n,pad}
  __shared__ float osum[256];
  int tid = threadIdx.x;
  int wave = tid >> 6, lane = tid & 63;
  int g = blockIdx.x & 7, s = blockIdx.x >> 3;

  // --- stationary W_hh fragments in registers (B-operand: n=lane&15, k=quad*8+j)
  short8 wfh[3][4], wfl[3][4];
  {
    int nloc = lane & 15;
    int kq = (lane >> 4) * 8;
    #pragma unroll
    for (int gt = 0; gt < 3; ++gt) {
      const float* wr = w_hh + (size_t)(gt * H_N + s * 16 + nloc) * H_N;
      #pragma unroll
      for (int ks = 0; ks < 4; ++ks) {
        int k0 = wave * 128 + ks * 32 + kq;
        short8 h8, l8;
        #pragma unroll
        for (int j = 0; j < 8; ++j) {
          float wv = wr[k0 + j];
          unsigned short hi = f32_to_bf16(wv);
          unsigned short lo = f32_to_bf16(wv - bf16_to_f32(hi));
          h8[j] = (short)hi; l8[j] = (short)lo;
        }
        wfh[gt][ks] = h8; wfl[gt][ks] = l8;
      }
    }
  }
  // --- per-thread gate constants: thread = (bb, jj)
  int bb = tid >> 4, jj = tid & 15;
  int jr = s * 16 + jj;
  float wihr = w_ih[jr], wihz = w_ih[H_N + jr], wihn = w_ih[2*H_N + jr];
  float bir = b_ih[jr],  biz = b_ih[H_N + jr],  bin_ = b_ih[2*H_N + jr];
  float bhr = b_hh[jr],  bhz = b_hh[H_N + jr],  bhn = b_hh[2*H_N + jr];
  float fcw = fc_w[jr];
  int gb = g * 16 + bb;
  float h_old = 0.f;
  // per-wave 8-flag poll (R15a; neutral but harmless)
  const unsigned int* fp = bars + g * 32 + wave * 8 + (lane & 7);
  unsigned int* myflag = bars + g * 32 + s;

  // producer indexing: j = s*16+jj
  //   fragment C = g*16 + (s>>3)*4 + ((s>>1)&3); q = (2s + (jj>>3))&3
  const int Cp = g * 16 + (s >> 3) * 4 + ((s >> 1) & 3);
  const int qp = (2 * s + (jj >> 3)) & 3;
  const size_t prodoff = (size_t)Cp * 512 + (size_t)qp * 128 + (size_t)bb * 8;
  // consumer base (ushort offset within parity's hi array)
  const size_t cbase = (size_t)(g * 16 + wave * 4) * 512 + (size_t)lane * 8;

  for (int t = 0; t < S_LEN; ++t) {
    // feats load hoisted above the poll — independent, overlaps the spin
    float x = feats[t * B_N + gb];
    float sr = 0.f, sz = 0.f, sn = 0.f;
    if (t > 0) {
      // ---- wait: this wave's 8 producers stored h_{t-1} (flag >= t)
      {
        const unsigned tgt = (unsigned)t;
        for (;;) {
          unsigned f = __hip_atomic_load(fp, __ATOMIC_RELAXED, __HIP_MEMORY_SCOPE_AGENT);
          if (__ballot(f < tgt) == 0ull) break;
          __builtin_amdgcn_s_sleep(1);
        }
        asm volatile("" ::: "memory");
      }
      const unsigned short* hh =
          (const unsigned short*)(hq + (size_t)((t - 1) & 1) * HW64);
      const unsigned short* hbase = hh + cbase;        // hi fragments
      const unsigned short* lbase = hbase + 65536;     // lo fragments
      // R16b: staged loads — h0,l0,h2,l2 first, then h1,l1,h3,l3.
      uint4v rh0, rl0, rh2, rl2, rh1, rl1, rh3, rl3;
      asm volatile(
        "global_load_dwordx4 %0, %8, off sc1\n\t"
        "global_load_dwordx4 %1, %9, off sc1\n\t"
        "global_load_dwordx4 %2, %8, off offset:2048 sc1\n\t"
        "global_load_dwordx4 %3, %9, off offset:2048 sc1\n\t"
        "global_load_dwordx4 %4, %8, off offset:1024 sc1\n\t"
        "global_load_dwordx4 %5, %9, off offset:1024 sc1\n\t"
        "global_load_dwordx4 %6, %8, off offset:3072 sc1\n\t"
        "global_load_dwordx4 %7, %9, off offset:3072 sc1"
        : "=&v"(rh0), "=&v"(rl0), "=&v"(rh2), "=&v"(rl2),
          "=&v"(rh1), "=&v"(rl1), "=&v"(rh3), "=&v"(rl3)
        : "v"(hbase), "v"(lbase));
      asm volatile("s_waitcnt vmcnt(4)");
      __builtin_amdgcn_sched_barrier(0);
      short8 ah0 = as_short8(rh0), al0 = as_short8(rl0);
      short8 ah2 = as_short8(rh2), al2 = as_short8(rl2);
      // R16a: 6 accumulator chains. b = ks{0,1}, c = ks{2,3}; a = b + c.
      float4v b0, b1, b2, c0, c1, c2;
      #pragma unroll
      for (int r = 0; r < 4; ++r) {
        b0[r] = 0.f; b1[r] = 0.f; b2[r] = 0.f;
        c0[r] = 0.f; c1[r] = 0.f; c2[r] = 0.f;
      }
      // ks=0 (b) and ks=2 (c), interleaved: same-acc spacing = 6 issues
      b0 = __builtin_amdgcn_mfma_f32_16x16x32_bf16(ah0, wfh[0][0], b0, 0,0,0);
      b1 = __builtin_amdgcn_mfma_f32_16x16x32_bf16(ah0, wfh[1][0], b1, 0,0,0);
      b2 = __builtin_amdgcn_mfma_f32_16x16x32_bf16(ah0, wfh[2][0], b2, 0,0,0);
      c0 = __builtin_amdgcn_mfma_f32_16x16x32_bf16(ah2, wfh[0][2], c0, 0,0,0);
      c1 = __builtin_amdgcn_mfma_f32_16x16x32_bf16(ah2, wfh[1][2], c1, 0,0,0);
      c2 = __builtin_amdgcn_mfma_f32_16x16x32_bf16(ah2, wfh[2][2], c2, 0,0,0);
      b0 = __builtin_amdgcn_mfma_f32_16x16x32_bf16(ah0, wfl[0][0], b0, 0,0,0);
      b1 = __builtin_amdgcn_mfma_f32_16x16x32_bf16(ah0, wfl[1][0], b1, 0,0,0);
      b2 = __builtin_amdgcn_mfma_f32_16x16x32_bf16(ah0, wfl[2][0], b2, 0,0,0);
      c0 = __builtin_amdgcn_mfma_f32_16x16x32_bf16(ah2, wfl[0][2], c0, 0,0,0);
      c1 = __builtin_amdgcn_mfma_f32_16x16x32_bf16(ah2, wfl[1][2], c1, 0,0,0);
      c2 = __builtin_amdgcn_mfma_f32_16x16x32_bf16(ah2, wfl[2][2], c2, 0,0,0);
      b0 = __builtin_amdgcn_mfma_f32_16x16x32_bf16(al0, wfh[0][0], b0, 0,0,0);
      b1 = __builtin_amdgcn_mfma_f32_16x16x32_bf16(al0, wfh[1][0], b1, 0,0,0);
      b2 = __builtin_amdgcn_mfma_f32_16x16x32_bf16(al0, wfh[2][0], b2, 0,0,0);
      c0 = __builtin_amdgcn_mfma_f32_16x16x32_bf16(al2, wfh[0][2], c0, 0,0,0);
      c1 = __builtin_amdgcn_mfma_f32_16x16x32_bf16(al2, wfh[1][2], c1, 0,0,0);
      c2 = __builtin_amdgcn_mfma_f32_16x16x32_bf16(al2, wfh[2][2], c2, 0,0,0);
      asm volatile("s_waitcnt vmcnt(0)");
      __builtin_amdgcn_sched_barrier(0);
      short8 ah1 = as_short8(rh1), al1 = as_short8(rl1);
      short8 ah3 = as_short8(rh3), al3 = as_short8(rl3);
      // ks=1 (b) and ks=3 (c)
      b0 = __builtin_amdgcn_mfma_f32_16x16x32_bf16(ah1, wfh[0][1], b0, 0,0,0);
      b1 = __builtin_amdgcn_mfma_f32_16x16x32_bf16(ah1, wfh[1][1], b1, 0,0,0);
      b2 = __builtin_amdgcn_mfma_f32_16x16x32_bf16(ah1, wfh[2][1], b2, 0,0,0);
      c0 = __builtin_amdgcn_mfma_f32_16x16x32_bf16(ah3, wfh[0][3], c0, 0,0,0);
      c1 = __builtin_amdgcn_mfma_f32_16x16x32_bf16(ah3, wfh[1][3], c1, 0,0,0);
      c2 = __builtin_amdgcn_mfma_f32_16x16x32_bf16(ah3, wfh[2][3], c2, 0,0,0);
      b0 = __builtin_amdgcn_mfma_f32_16x16x32_bf16(ah1, wfl[0][1], b0, 0,0,0);
      b1 = __builtin_amdgcn_mfma_f32_16x16x32_bf16(ah1, wfl[1][1], b1, 0,0,0);
      b2 = __builtin_amdgcn_mfma_f32_16x16x32_bf16(ah1, wfl[2][1], b2, 0,0,0);
      c0 = __builtin_amdgcn_mfma_f32_16x16x32_bf16(ah3, wfl[0][3], c0, 0,0,0);
      c1 = __builtin_amdgcn_mfma_f32_16x16x32_bf16(ah3, wfl[1][3], c1, 0,0,0);
      c2 = __builtin_amdgcn_mfma_f32_16x16x32_bf16(ah3, wfl[2][3], c2, 0,0,0);
      b0 = __builtin_amdgcn_mfma_f32_16x16x32_bf16(al1, wfh[0][1], b0, 0,0,0);
      b1 = __builtin_amdgcn_mfma_f32_16x16x32_bf16(al1, wfh[1][1], b1, 0,0,0);
      b2 = __builtin_amdgcn_mfma_f32_16x16x32_bf16(al1, wfh[2][1], b2, 0,0,0);
      c0 = __builtin_amdgcn_mfma_f32_16x16x32_bf16(al3, wfh[0][3], c0, 0,0,0);
      c1 = __builtin_amdgcn_mfma_f32_16x16x32_bf16(al3, wfh[1][3], c1, 0,0,0);
      c2 = __builtin_amdgcn_mfma_f32_16x16x32_bf16(al3, wfh[2][3], c2, 0,0,0);
      float4v a0 = b0 + c0, a1 = b1 + c1, a2 = b2 + c2;
      // C/D: row(batch)=(lane>>4)*4+reg, col(j)=lane&15. float4 {r,z,n,pad}.
      int colw = lane & 15, roww = (lane >> 4) * 4;
      #pragma unroll
      for (int r = 0; r < 4; ++r) {
        float4v w; w[0] = a0[r]; w[1] = a1[r]; w[2] = a2[r]; w[3] = 0.f;
        red2[wave][roww + r][colw] = w;
      }
      __syncthreads();
      float4v s0 = red2[0][bb][jj], s1 = red2[1][bb][jj];
      float4v s2 = red2[2][bb][jj], s3 = red2[3][bb][jj];
      sr = s0[0] + s1[0] + s2[0] + s3[0];
      sz = s0[1] + s1[1] + s2[1] + s3[1];
      sn = s0[2] + s1[2] + s2[2] + s3[2];
    }
    // gates: exact identities on fast exp; clamp to dodge inf/inf
    float ar_ = fminf(fmaxf(x * wihr + bir + sr + bhr, -30.f), 30.f);
    float az_ = fminf(fmaxf(x * wihz + biz + sz + bhz, -30.f), 30.f);
    float r_ = __builtin_amdgcn_rcpf(1.f + __expf(-ar_));
    float z_ = __builtin_amdgcn_rcpf(1.f + __expf(-az_));
    float an_ = fminf(fmaxf(x * wihn + bin_ + r_ * (sn + bhn), -30.f), 30.f);
    float en = __expf(-2.f * an_);
    float n_ = (1.f - en) * __builtin_amdgcn_rcpf(1.f + en);
    float h_new = (1.f - z_) * n_ + z_ * h_old;
    h_old = h_new;
    if (t < S_LEN - 1) {
      unsigned short hi16 = f32_to_bf16(h_new);
      unsigned short lo16 = f32_to_bf16(h_new - bf16_to_f32(hi16));
      // 3-round shfl_xor allgather -> full 8-elem run in 4 dwords.
      unsigned myh = hi16, myl = lo16;
      unsigned oh = (unsigned)__shfl_xor((int)myh, 1);
      unsigned ol = (unsigned)__shfl_xor((int)myl, 1);
      bool od1 = (jj & 1) != 0;
      unsigned pH = od1 ? (oh | (myh << 16)) : (myh | (oh << 16));  // [e even|e odd]
      unsigned pL = od1 ? (ol | (myl << 16)) : (myl | (ol << 16));
      unsigned qh = (unsigned)__shfl_xor((int)pH, 2);
      unsigned ql = (unsigned)__shfl_xor((int)pL, 2);
      bool od2 = (jj & 2) != 0;
      unsigned h01 = od2 ? qh : pH, h23 = od2 ? pH : qh;   // pairs e01,e23 of 4-group
      unsigned l01 = od2 ? ql : pL, l23 = od2 ? pL : ql;
      unsigned xh01 = (unsigned)__shfl_xor((int)h01, 4);
      unsigned xh23 = (unsigned)__shfl_xor((int)h23, 4);
      unsigned xl01 = (unsigned)__shfl_xor((int)l01, 4);
      unsigned xl23 = (unsigned)__shfl_xor((int)l23, 4);
      bool od4 = (jj & 4) != 0;
      uint4v runH, runL;
      runH[0] = od4 ? xh01 : h01; runH[1] = od4 ? xh23 : h23;
      runH[2] = od4 ? h01 : xh01; runH[3] = od4 ? h23 : xh23;
      runL[0] = od4 ? xl01 : l01; runL[1] = od4 ? xl23 : l23;
      runL[2] = od4 ? l01 : xl01; runL[3] = od4 ? l23 : xl23;
      unsigned short* hh = (unsigned short*)(hq + (size_t)(t & 1) * HW64);
      if ((jj & 3) == 0) {   // jj=0,8: hi run; jj=4,12: lo run
        if ((jj & 4) == 0) *(uint4v*)(hh + prodoff)         = runH;
        else               *(uint4v*)(hh + 65536 + prodoff) = runL;
      }
      // drain own stores (ack at L2), WG barrier, then flag (wg-scope)
      asm volatile("s_waitcnt vmcnt(0)" ::: "memory");
      __syncthreads();
      if (tid == 0)
        __hip_atomic_store(myflag, (unsigned)(t + 1),
                           __ATOMIC_RELAXED, __HIP_MEMORY_SCOPE_WORKGROUP);
    }
  }
  // --- epilogue: out[b] = h_last . fc_w + fc_b
  osum[tid] = h_old * fcw;
  __syncthreads();
  if (jj == 0) {
    float acc = 0.f;
    #pragma unroll
    for (int q = 0; q < 16; ++q) acc += osum[bb * 16 + q];
    if (s == 0) acc += fc_b[0];
    atomicAdd(&out[gb], acc);
  }
}

// ---------------------------------------------------------------------------
extern "C" void kernel_launch(void* const* d_in, const int* in_sizes, int n_in,
                              void* d_out, int out_size, void* d_ws, size_t ws_size,
                              hipStream_t stream) {
  (void)in_sizes; (void)n_in; (void)out_size; (void)ws_size;
  const int*   ends = (const int*)d_in[1];
  const float* emb  = (const float*)d_in[3];
  const float* w_ih = (const float*)d_in[4];
  const float* w_hh = (const float*)d_in[5];
  const float* b_ih = (const float*)d_in[6];
  const float* b_hh = (const float*)d_in[7];
  const float* fc_w = (const float*)d_in[8];
  const float* fc_b = (const float*)d_in[9];
  float* out = (float*)d_out;

  size_t xn_elems = (size_t)B_N * S_LEN * KP;
  unsigned short* xh = (unsigned short*)d_ws;
  unsigned short* xl = xh + xn_elems;
  float* feats = (float*)(xl + xn_elems);
  unsigned long long* hq = (unsigned long long*)(feats + S_LEN * B_N);
  unsigned int* bars = (unsigned int*)(hq + 2 * (size_t)HW64);

  hipMemsetAsync(out, 0, sizeof(float) * B_N, stream);
  hipMemsetAsync(bars, 0, 4096, stream);   // 8 groups x 32 WG flags

  k1_embed_norm<<<dim3(S_LEN * B_N / 4), dim3(256), 0, stream>>>(ends, emb, xh, xl);
  k2_feats<<<dim3(B_N, 8), dim3(256), 0, stream>>>(xh, xl, feats);

  void* args[] = { (void*)&feats, (void*)&w_ih, (void*)&w_hh, (void*)&b_ih,
                   (void*)&b_hh, (void*)&fc_w, (void*)&fc_b,
                   (void*)&hq, (void*)&bars, (void*)&out };
  hipLaunchCooperativeKernel((void*)k3_gru, dim3(256), dim3(256), args, 0, stream);
}

// Round 6
// 1092.526 us; speedup vs baseline: 1.0397x; 1.0397x over previous
//
#include <hip/hip_runtime.h>
#include <hip/hip_bf16.h>
#include <math.h>

// Problem: S=512, B=128, V=50257, D=300, H=512
#define S_LEN 512
#define B_N   128
#define D_EMB 300
#define KP    320   // D padded to multiple of 32 (zero-filled)
#define H_N   512

typedef __attribute__((ext_vector_type(8)))  short short8;       // 8 bf16 (4 VGPRs)
typedef __attribute__((ext_vector_type(8)))  unsigned short ushort8;
typedef __attribute__((ext_vector_type(4)))  unsigned int uint4v;
typedef __attribute__((ext_vector_type(4)))  float float4v;
typedef __attribute__((ext_vector_type(16))) float float16v;

__device__ __forceinline__ unsigned short f32_to_bf16(float f) {
  unsigned u = __float_as_uint(f);
  u = (u + 0x7fffu + ((u >> 16) & 1u)) >> 16;   // RNE
  return (unsigned short)u;
}
__device__ __forceinline__ float bf16_to_f32(unsigned short h) {
  return __uint_as_float(((unsigned)h) << 16);
}
__device__ __forceinline__ short8 as_short8(uint4v v) {
  union { uint4v u; short8 s; } c; c.u = v; return c.s;
}

// ---------------------------------------------------------------------------
// K1: embeds = embed_mat[ends]; xn = embeds / max(||embeds||,eps)
// writes xn as split bf16 (hi+lo), layout [b][s][KP], k 300..319 zero.
// ---------------------------------------------------------------------------
__global__ __launch_bounds__(256) void k1_embed_norm(
    const int* __restrict__ ends, const float* __restrict__ emb,
    unsigned short* __restrict__ xh, unsigned short* __restrict__ xl) {
  int wave = threadIdx.x >> 6, lane = threadIdx.x & 63;
  int vec = blockIdx.x * 4 + wave;            // vec = s*B + b (ends is [S][B])
  int b = vec & (B_N - 1), s = vec >> 7;
  int v = ends[vec];
  const float* row = emb + (size_t)v * D_EMB;
  float e0 = row[lane], e1 = row[lane + 64], e2 = row[lane + 128], e3 = row[lane + 192];
  float e4 = (lane + 256 < D_EMB) ? row[lane + 256] : 0.f;
  float ss = e0*e0 + e1*e1 + e2*e2 + e3*e3 + e4*e4;
  #pragma unroll
  for (int m = 1; m < 64; m <<= 1) ss += __shfl_xor(ss, m);
  float sc = 1.0f / fmaxf(sqrtf(ss), 1e-8f);
  size_t base = ((size_t)b * S_LEN + s) * KP;
  float xs[5] = { e0*sc, e1*sc, e2*sc, e3*sc, (lane + 256 < D_EMB) ? e4*sc : 0.f };
  #pragma unroll
  for (int i = 0; i < 5; ++i) {
    unsigned short hi = f32_to_bf16(xs[i]);
    unsigned short lo = f32_to_bf16(xs[i] - bf16_to_f32(hi));
    xh[base + lane + 64*i] = hi;
    xl[base + lane + 64*i] = lo;
  }
}

// ---------------------------------------------------------------------------
// K2: feats[i][b] = max_{j<i} dot(xn[i,b], xn[j,b]); feats[0]=0
// Split-bf16 MFMA 32x32x16 (hi*hi + hi*lo + lo*hi).
// R11: A-operand fragments loaded straight from global into registers
// (identical element mapping as the old LDS path; L2-hot after jc=0),
// LDS stages only B (22.5KB -> ~2x co-residency), grid is (b, ic) so all
// ic-chunks of a batch share one XCD L2 (same %8 mapping k3 relies on).
// ---------------------------------------------------------------------------
#define KC  80
#define LDP 88      // LDS row stride in ushorts (conflict-friendly, 16B aligned)

__global__ __launch_bounds__(256) void k2_feats(
    const unsigned short* __restrict__ xh, const unsigned short* __restrict__ xl,
    float* __restrict__ feats) {
  __shared__ __align__(16) unsigned short sBh[64*LDP], sBl[64*LDP];
  __shared__ float rbuf[4][32];
  int b   = blockIdx.x;          // 0..127 (b&7 selects XCD)
  int ic  = blockIdx.y;          // 0..7
  int tid = threadIdx.x;
  int wave = tid >> 6, lane = tid & 63;
  int itl = wave & 1, jtl = wave >> 1;
  int itg = ic * 2 + itl;        // global 32-row i-tile index
  size_t xbase = (size_t)b * S_LEN * KP;
  int arow0 = ic * 64;
  // my A row (m = lane&31) and k-quad offset
  const size_t arowoff = xbase + (size_t)(arow0 + itl * 32 + (lane & 31)) * KP
                       + (size_t)((lane >> 5) * 8);

  float rm[16];
  #pragma unroll
  for (int r = 0; r < 16; ++r) rm[r] = -INFINITY;

  for (int jc = 0; jc <= ic; ++jc) {
    int jt = jc * 2 + jtl;
    bool active = (jt <= itg);
    float16v acc;
    #pragma unroll
    for (int r = 0; r < 16; ++r) acc[r] = 0.f;

    for (int kc = 0; kc < 4; ++kc) {
      // A fragments: direct global->register (10 x 16B per lane)
      short8 a_h[5], a_l[5];
      #pragma unroll
      for (int ks = 0; ks < 5; ++ks) {
        size_t ga = arowoff + kc * KC + ks * 16;
        a_h[ks] = *(const short8*)&xh[ga];
        a_l[ks] = *(const short8*)&xl[ga];
      }
      __syncthreads();
      for (int u = tid; u < 640; u += 256) {     // 64 rows x 10 16B-segs (B only)
        int r = u / 10, sg = u % 10;
        size_t gb = xbase + (size_t)(jc*64 + r) * KP + kc*KC + sg*8;
        int la = r * LDP + sg * 8;
        *(ushort8*)&sBh[la] = *(const ushort8*)&xh[gb];
        *(ushort8*)&sBl[la] = *(const ushort8*)&xl[gb];
      }
      __syncthreads();
      if (active) {
        int br = (jtl*32 + (lane & 31)) * LDP;
        int kq = (lane >> 5) * 8;
        #pragma unroll
        for (int ks = 0; ks < 5; ++ks) {
          short8 b_h = *(const short8*)&sBh[br + ks*16 + kq];
          short8 b_l = *(const short8*)&sBl[br + ks*16 + kq];
          acc = __builtin_amdgcn_mfma_f32_32x32x16_bf16(a_h[ks], b_h, acc, 0, 0, 0);
          acc = __builtin_amdgcn_mfma_f32_32x32x16_bf16(a_h[ks], b_l, acc, 0, 0, 0);
          acc = __builtin_amdgcn_mfma_f32_32x32x16_bf16(a_l[ks], b_h, acc, 0, 0, 0);
        }
      }
    }
    if (active) {
      int colg = jt * 32 + (lane & 31);
      #pragma unroll
      for (int r = 0; r < 16; ++r) {
        int rowg = itg * 32 + (r & 3) + 8*(r >> 2) + 4*(lane >> 5);
        float v = acc[r];
        if (jt == itg && colg >= rowg) v = -INFINITY;  // causal: j<i
        rm[r] = fmaxf(rm[r], v);
      }
    }
  }
  #pragma unroll
  for (int r = 0; r < 16; ++r) {
    float v = rm[r];
    v = fmaxf(v, __shfl_xor(v, 1));
    v = fmaxf(v, __shfl_xor(v, 2));
    v = fmaxf(v, __shfl_xor(v, 4));
    v = fmaxf(v, __shfl_xor(v, 8));
    v = fmaxf(v, __shfl_xor(v, 16));
    rm[r] = v;
  }
  if ((lane & 31) == 0) {
    int half = lane >> 5;
    #pragma unroll
    for (int r = 0; r < 16; ++r)
      rbuf[wave][(r & 3) + 8*(r >> 2) + 4*half] = rm[r];
  }
  __syncthreads();
  if (tid < 64) {   // merge jt-parities, write feats
    int it2 = tid >> 5, rl = tid & 31;
    float v = fmaxf(rbuf[it2][rl], rbuf[it2 + 2][rl]);
    int i = ic * 64 + it2 * 32 + rl;
    feats[i * B_N + b] = (i == 0) ? 0.0f : v;
  }
}

// ---------------------------------------------------------------------------
// K3: GRU, persistent cooperative kernel. 256 WGs x 512 thr (R17).
// FROZEN R8 signal skeleton: wg-scope producer stores -> vmcnt(0) ->
// __syncthreads -> tid0 WG-flag store; consumer flag poll with s_sleep.
// LEDGER: per-wave PRODUCER flag fanouts fast-fail 3/3 (R5/R6/R9);
// counter-RMW flags regress (R10); poison-spin data-as-signal +16% (R12);
// R13 coalesced consumer load -360us; R14 fragment-major layout -253us;
// R15 bank-conflict-free reduce (2.5e7->0) only -19us (conflicts were
// overlapped); R16 chain-split + staged vmcnt REGRESSED +24us and MfmaUtil
// didn't move -> the ~16cy/MFMA is single-wave ISSUE occupancy, not dep
// stalls (kernel ran 1 wave/SIMD).
// R17 (this round): 512 threads = 8 waves = 2 waves/SIMD. Each wave does
// K=64 (2 fragments, 4 dwordx4 loads, 18 MFMAs); two waves per SIMD
// interleave MFMA issue -> MFMA section ~halves, and one wave's L2 load
// latency hides under the other's compute. red2 becomes 8-partial
// (reads guarded to the 256 gate threads). Producer protocol, hq layout,
// pack, flags: byte-identical to R15. Per-wave poll = its 4 producers
// (fragment<->producer map verified: wave w needs s in [4w,4w+4)).
// ---------------------------------------------------------------------------
#define HW64 (B_N * H_N / 2)   // 8B words per parity buffer (= 32768)

__global__ __launch_bounds__(512, 1) void k3_gru(
    const float* __restrict__ feats,
    const float* __restrict__ w_ih, const float* __restrict__ w_hh,
    const float* __restrict__ b_ih, const float* __restrict__ b_hh,
    const float* __restrict__ fc_w, const float* __restrict__ fc_b,
    unsigned long long* __restrict__ hq, unsigned int* __restrict__ bars,
    float* __restrict__ out) {
  __shared__ __align__(16) float4v red2[8][16][16];   // [wave][batch][j] = {r,z,n,pad}
  __shared__ float osum[256];
  int tid = threadIdx.x;
  int wave = tid >> 6, lane = tid & 63;
  int g = blockIdx.x & 7, s = blockIdx.x >> 3;

  // --- stationary W_hh fragments in registers (B-operand: n=lane&15, k=quad*8+j)
  // wave w covers global K slice [64w, 64w+64): ks in {0,1} local.
  short8 wfh[3][2], wfl[3][2];
  {
    int nloc = lane & 15;
    int kq = (lane >> 4) * 8;
    #pragma unroll
    for (int gt = 0; gt < 3; ++gt) {
      const float* wr = w_hh + (size_t)(gt * H_N + s * 16 + nloc) * H_N;
      #pragma unroll
      for (int ks = 0; ks < 2; ++ks) {
        int k0 = wave * 64 + ks * 32 + kq;
        short8 h8, l8;
        #pragma unroll
        for (int j = 0; j < 8; ++j) {
          float wv = wr[k0 + j];
          unsigned short hi = f32_to_bf16(wv);
          unsigned short lo = f32_to_bf16(wv - bf16_to_f32(hi));
          h8[j] = (short)hi; l8[j] = (short)lo;
        }
        wfh[gt][ks] = h8; wfl[gt][ks] = l8;
      }
    }
  }
  // --- per-thread gate constants: gate thread = (bb, jj), tid<256 only
  const bool gater = (tid < 256);
  int bb = tid >> 4, jj = tid & 15;           // bb valid as batch only if gater
  int jr = s * 16 + jj;
  float wihr = w_ih[jr], wihz = w_ih[H_N + jr], wihn = w_ih[2*H_N + jr];
  float bir = b_ih[jr],  biz = b_ih[H_N + jr],  bin_ = b_ih[2*H_N + jr];
  float bhr = b_hh[jr],  bhz = b_hh[H_N + jr],  bhn = b_hh[2*H_N + jr];
  float fcw = fc_w[jr];
  int gb = g * 16 + (bb & 15);
  float h_old = 0.f;
  // R17: wave w polls only its 4 producers s in [4w, 4w+4)
  const unsigned int* fp = bars + g * 32 + wave * 4 + (lane & 3);
  unsigned int* myflag = bars + g * 32 + s;

  // producer indexing (unchanged): j = s*16+jj
  //   fragment C = g*16 + (s>>3)*4 + ((s>>1)&3); q = (2s + (jj>>3))&3
  const int Cp = g * 16 + (s >> 3) * 4 + ((s >> 1) & 3);
  const int qp = (2 * s + (jj >> 3)) & 3;
  const size_t prodoff = (size_t)Cp * 512 + (size_t)qp * 128 + (size_t)(bb & 15) * 8;
  // consumer base: wave w owns fragments 2w, 2w+1
  const size_t cbase = (size_t)(g * 16 + wave * 2) * 512 + (size_t)lane * 8;

  for (int t = 0; t < S_LEN; ++t) {
    // feats load hoisted above the poll — independent, overlaps the spin
    float x = gater ? feats[t * B_N + gb] : 0.f;
    float sr = 0.f, sz = 0.f, sn = 0.f;
    if (t > 0) {
      // ---- wait: this wave's 4 producers stored h_{t-1} (flag >= t)
      {
        const unsigned tgt = (unsigned)t;
        for (;;) {
          unsigned f = __hip_atomic_load(fp, __ATOMIC_RELAXED, __HIP_MEMORY_SCOPE_AGENT);
          if (__ballot(f < tgt) == 0ull) break;
          __builtin_amdgcn_s_sleep(1);
        }
        asm volatile("" ::: "memory");
      }
      const unsigned short* hh =
          (const unsigned short*)(hq + (size_t)((t - 1) & 1) * HW64);
      const unsigned short* hbase = hh + cbase;        // hi fragments
      const unsigned short* lbase = hbase + 65536;     // lo fragments
      // 4x dwordx4 sc1 (L1-bypass), each 64-lane instr = 1KB contiguous.
      uint4v rh0, rh1, rl0, rl1;
      asm volatile(
        "global_load_dwordx4 %0, %4, off sc1\n\t"
        "global_load_dwordx4 %1, %4, off offset:1024 sc1\n\t"
        "global_load_dwordx4 %2, %5, off sc1\n\t"
        "global_load_dwordx4 %3, %5, off offset:1024 sc1\n\t"
        "s_waitcnt vmcnt(0)"
        : "=&v"(rh0), "=&v"(rh1), "=&v"(rl0), "=&v"(rl1)
        : "v"(hbase), "v"(lbase)
        : "memory");
      short8 ah0 = as_short8(rh0), ah1 = as_short8(rh1);
      short8 al0 = as_short8(rl0), al1 = as_short8(rl1);
      float4v a0, a1, a2;
      #pragma unroll
      for (int r = 0; r < 4; ++r) { a0[r] = 0.f; a1[r] = 0.f; a2[r] = 0.f; }
      // 18 MFMAs: 2 local ks x {hh, hl, lh} x 3 gates (same per-ks order as R15)
      a0 = __builtin_amdgcn_mfma_f32_16x16x32_bf16(ah0, wfh[0][0], a0, 0,0,0);
      a1 = __builtin_amdgcn_mfma_f32_16x16x32_bf16(ah0, wfh[1][0], a1, 0,0,0);
      a2 = __builtin_amdgcn_mfma_f32_16x16x32_bf16(ah0, wfh[2][0], a2, 0,0,0);
      a0 = __builtin_amdgcn_mfma_f32_16x16x32_bf16(ah0, wfl[0][0], a0, 0,0,0);
      a1 = __builtin_amdgcn_mfma_f32_16x16x32_bf16(ah0, wfl[1][0], a1, 0,0,0);
      a2 = __builtin_amdgcn_mfma_f32_16x16x32_bf16(ah0, wfl[2][0], a2, 0,0,0);
      a0 = __builtin_amdgcn_mfma_f32_16x16x32_bf16(al0, wfh[0][0], a0, 0,0,0);
      a1 = __builtin_amdgcn_mfma_f32_16x16x32_bf16(al0, wfh[1][0], a1, 0,0,0);
      a2 = __builtin_amdgcn_mfma_f32_16x16x32_bf16(al0, wfh[2][0], a2, 0,0,0);
      a0 = __builtin_amdgcn_mfma_f32_16x16x32_bf16(ah1, wfh[0][1], a0, 0,0,0);
      a1 = __builtin_amdgcn_mfma_f32_16x16x32_bf16(ah1, wfh[1][1], a1, 0,0,0);
      a2 = __builtin_amdgcn_mfma_f32_16x16x32_bf16(ah1, wfh[2][1], a2, 0,0,0);
      a0 = __builtin_amdgcn_mfma_f32_16x16x32_bf16(ah1, wfl[0][1], a0, 0,0,0);
      a1 = __builtin_amdgcn_mfma_f32_16x16x32_bf16(ah1, wfl[1][1], a1, 0,0,0);
      a2 = __builtin_amdgcn_mfma_f32_16x16x32_bf16(ah1, wfl[2][1], a2, 0,0,0);
      a0 = __builtin_amdgcn_mfma_f32_16x16x32_bf16(al1, wfh[0][1], a0, 0,0,0);
      a1 = __builtin_amdgcn_mfma_f32_16x16x32_bf16(al1, wfh[1][1], a1, 0,0,0);
      a2 = __builtin_amdgcn_mfma_f32_16x16x32_bf16(al1, wfh[2][1], a2, 0,0,0);
      // C/D: row(batch)=(lane>>4)*4+reg, col(j)=lane&15. float4 {r,z,n,pad}.
      int colw = lane & 15, roww = (lane >> 4) * 4;
      #pragma unroll
      for (int r = 0; r < 4; ++r) {
        float4v w; w[0] = a0[r]; w[1] = a1[r]; w[2] = a2[r]; w[3] = 0.f;
        red2[wave][roww + r][colw] = w;
      }
      __syncthreads();
      if (gater) {
        float4v sv = red2[0][bb][jj];
        #pragma unroll
        for (int w8 = 1; w8 < 8; ++w8) sv += red2[w8][bb][jj];
        sr = sv[0]; sz = sv[1]; sn = sv[2];
      }
    }
    if (gater) {
      // gates: exact identities on fast exp; clamp to dodge inf/inf
      float ar_ = fminf(fmaxf(x * wihr + bir + sr + bhr, -30.f), 30.f);
      float az_ = fminf(fmaxf(x * wihz + biz + sz + bhz, -30.f), 30.f);
      float r_ = __builtin_amdgcn_rcpf(1.f + __expf(-ar_));
      float z_ = __builtin_amdgcn_rcpf(1.f + __expf(-az_));
      float an_ = fminf(fmaxf(x * wihn + bin_ + r_ * (sn + bhn), -30.f), 30.f);
      float en = __expf(-2.f * an_);
      float n_ = (1.f - en) * __builtin_amdgcn_rcpf(1.f + en);
      float h_new = (1.f - z_) * n_ + z_ * h_old;
      h_old = h_new;
      if (t < S_LEN - 1) {
        unsigned short hi16 = f32_to_bf16(h_new);
        unsigned short lo16 = f32_to_bf16(h_new - bf16_to_f32(hi16));
        // 3-round shfl_xor allgather -> full 8-elem run in 4 dwords.
        unsigned myh = hi16, myl = lo16;
        unsigned oh = (unsigned)__shfl_xor((int)myh, 1);
        unsigned ol = (unsigned)__shfl_xor((int)myl, 1);
        bool od1 = (jj & 1) != 0;
        unsigned pH = od1 ? (oh | (myh << 16)) : (myh | (oh << 16));  // [e even|e odd]
        unsigned pL = od1 ? (ol | (myl << 16)) : (myl | (ol << 16));
        unsigned qh = (unsigned)__shfl_xor((int)pH, 2);
        unsigned ql = (unsigned)__shfl_xor((int)pL, 2);
        bool od2 = (jj & 2) != 0;
        unsigned h01 = od2 ? qh : pH, h23 = od2 ? pH : qh;   // pairs e01,e23
        unsigned l01 = od2 ? ql : pL, l23 = od2 ? pL : ql;
        unsigned xh01 = (unsigned)__shfl_xor((int)h01, 4);
        unsigned xh23 = (unsigned)__shfl_xor((int)h23, 4);
        unsigned xl01 = (unsigned)__shfl_xor((int)l01, 4);
        unsigned xl23 = (unsigned)__shfl_xor((int)l23, 4);
        bool od4 = (jj & 4) != 0;
        uint4v runH, runL;
        runH[0] = od4 ? xh01 : h01; runH[1] = od4 ? xh23 : h23;
        runH[2] = od4 ? h01 : xh01; runH[3] = od4 ? h23 : xh23;
        runL[0] = od4 ? xl01 : l01; runL[1] = od4 ? xl23 : l23;
        runL[2] = od4 ? l01 : xl01; runL[3] = od4 ? l23 : xl23;
        unsigned short* hh = (unsigned short*)(hq + (size_t)(t & 1) * HW64);
        if ((jj & 3) == 0) {   // jj=0,8: hi run; jj=4,12: lo run
          if ((jj & 4) == 0) *(uint4v*)(hh + prodoff)         = runH;
          else               *(uint4v*)(hh + 65536 + prodoff) = runL;
        }
      }
    }
    if (t < S_LEN - 1) {
      // drain own stores (ack at L2), WG barrier, then flag (wg-scope)
      asm volatile("s_waitcnt vmcnt(0)" ::: "memory");
      __syncthreads();
      if (tid == 0)
        __hip_atomic_store(myflag, (unsigned)(t + 1),
                           __ATOMIC_RELAXED, __HIP_MEMORY_SCOPE_WORKGROUP);
    }
  }
  // --- epilogue: out[b] = h_last . fc_w + fc_b
  if (gater) osum[tid] = h_old * fcw;
  __syncthreads();
  if (gater && jj == 0) {
    float acc = 0.f;
    #pragma unroll
    for (int q = 0; q < 16; ++q) acc += osum[bb * 16 + q];
    if (s == 0) acc += fc_b[0];
    atomicAdd(&out[gb], acc);
  }
}

// ---------------------------------------------------------------------------
extern "C" void kernel_launch(void* const* d_in, const int* in_sizes, int n_in,
                              void* d_out, int out_size, void* d_ws, size_t ws_size,
                              hipStream_t stream) {
  (void)in_sizes; (void)n_in; (void)out_size; (void)ws_size;
  const int*   ends = (const int*)d_in[1];
  const float* emb  = (const float*)d_in[3];
  const float* w_ih = (const float*)d_in[4];
  const float* w_hh = (const float*)d_in[5];
  const float* b_ih = (const float*)d_in[6];
  const float* b_hh = (const float*)d_in[7];
  const float* fc_w = (const float*)d_in[8];
  const float* fc_b = (const float*)d_in[9];
  float* out = (float*)d_out;

  size_t xn_elems = (size_t)B_N * S_LEN * KP;
  unsigned short* xh = (unsigned short*)d_ws;
  unsigned short* xl = xh + xn_elems;
  float* feats = (float*)(xl + xn_elems);
  unsigned long long* hq = (unsigned long long*)(feats + S_LEN * B_N);
  unsigned int* bars = (unsigned int*)(hq + 2 * (size_t)HW64);

  hipMemsetAsync(out, 0, sizeof(float) * B_N, stream);
  hipMemsetAsync(bars, 0, 4096, stream);   // 8 groups x 32 WG flags

  k1_embed_norm<<<dim3(S_LEN * B_N / 4), dim3(256), 0, stream>>>(ends, emb, xh, xl);
  k2_feats<<<dim3(B_N, 8), dim3(256), 0, stream>>>(xh, xl, feats);

  void* args[] = { (void*)&feats, (void*)&w_ih, (void*)&w_hh, (void*)&b_ih,
                   (void*)&b_hh, (void*)&fc_w, (void*)&fc_b,
                   (void*)&hq, (void*)&bars, (void*)&out };
  hipLaunchCooperativeKernel((void*)k3_gru, dim3(256), dim3(512), args, 0, stream);
}